// Round 4
// baseline (389.240 us; speedup 1.0000x reference)
//
#include <hip/hip_runtime.h>

#define N_NODES 50000
#define N_EDGES 1600000
#define N_CAND  131072
#define D 128
#define ROWS 50176   // padded row count
#define NB 196       // coarse buckets (dst>>8)
#define BCAP 10240   // fixed per-bucket capacity (E[cnt]=8192, sigma~90)
#define LSTR 132     // LDS row stride (bf16 elems)
#define ZROW 50000   // zeroed row: /dev/null target for padded gather slots

typedef __attribute__((ext_vector_type(8))) short short8;
typedef __attribute__((ext_vector_type(4))) float f32x4;

__device__ inline short f2bf(float f) {
  unsigned u = __builtin_bit_cast(unsigned, f);
  u = (u + 0x7FFFu + ((u >> 16) & 1u)) >> 16;
  return (short)u;
}
__device__ inline float bf_lo(unsigned u) { return __builtin_bit_cast(float, u << 16); }
__device__ inline float bf_hi(unsigned u) { return __builtin_bit_cast(float, u & 0xFFFF0000u); }
__device__ inline float bfu(unsigned short h) { return __builtin_bit_cast(float, (unsigned)h << 16); }

// ---------------- prep + pass1 merged (unchanged) ----------------

__global__ __launch_bounds__(256) void prep_pass1(const float* __restrict__ gw1,
                                                  const float* __restrict__ gw2,
                                                  const float* __restrict__ pw1,
                                                  short* __restrict__ Wf,
                                                  const float* __restrict__ x,
                                                  unsigned short* __restrict__ y,
                                                  const int* __restrict__ src,
                                                  const int* __restrict__ dst,
                                                  int* __restrict__ bucket_cnt,
                                                  int* __restrict__ pairs) {
  int b = blockIdx.x;
  int t = threadIdx.x;
  if (b < 64) {
    int tid = b * 256 + t;  // 0..16383
    int img = tid >> 11, idx = tid & 2047;
    const float* W;
    if (img < 3) W = gw1 + img * 16384;
    else if (img < 6) W = gw2 + (img - 3) * 16384;
    else W = pw1 + (256 + (img - 6) * 128) * 128;
    int n = idx & 127, k8 = idx >> 7;
    short8 s;
#pragma unroll
    for (int j = 0; j < 8; ++j) s[j] = f2bf(W[(k8 * 8 + j) * 128 + n]);
    int kk = k8 >> 2, q = k8 & 3, nt = n >> 4, ln = (n & 15) | (q << 4);
    *(short8*)&Wf[img * 16384 + ((nt * 4 + kk) * 64 + ln) * 8] = s;
  } else if (b < 3189) {
    size_t base = ((size_t)(b - 64) * 256 + t) * 8;
    float4 v0 = *(const float4*)&x[base];
    float4 v1 = *(const float4*)&x[base + 4];
    short8 s;
    s[0] = f2bf(v0.x); s[1] = f2bf(v0.y); s[2] = f2bf(v0.z); s[3] = f2bf(v0.w);
    s[4] = f2bf(v1.x); s[5] = f2bf(v1.y); s[6] = f2bf(v1.z); s[7] = f2bf(v1.w);
    *(short8*)&y[base] = s;
  } else {
    __shared__ int lcnt[NB];
    __shared__ int loff[NB];
    __shared__ int gbase[NB];
    __shared__ int scanbuf[256];
    __shared__ int stage[4096];
    int e0 = (b - 3189) * 4096;
    for (int i = t; i < NB; i += 256) lcnt[i] = 0;
    __syncthreads();
    int d[16], s[16], r[16];
#pragma unroll
    for (int i = 0; i < 16; ++i) {
      int e = e0 + i * 256 + t;
      if (e < N_EDGES) {
        d[i] = dst[e]; s[i] = src[e];
        r[i] = atomicAdd(&lcnt[d[i] >> 8], 1);
      } else d[i] = -1;
    }
    __syncthreads();
    {
      int v = (t < NB) ? lcnt[t] : 0;
      scanbuf[t] = v;
      __syncthreads();
      for (int off = 1; off < 256; off <<= 1) {
        int add = (t >= off) ? scanbuf[t - off] : 0;
        __syncthreads();
        scanbuf[t] += add;
        __syncthreads();
      }
      if (t < NB) {
        loff[t] = scanbuf[t] - v;
        gbase[t] = v ? atomicAdd(&bucket_cnt[t], v) : 0;
      }
    }
    __syncthreads();
#pragma unroll
    for (int i = 0; i < 16; ++i) {
      if (d[i] >= 0) {
        int bb = d[i] >> 8;
        stage[loff[bb] + r[i]] = (s[i] << 8) | (d[i] & 255);
      }
    }
    __syncthreads();
    int w = t >> 6, lane = t & 63;
    for (int bb = w; bb < NB; bb += 4) {
      int c = lcnt[bb], lo = loff[bb], gb = bb * BCAP + gbase[bb];
      for (int k = lane; k < c; k += 64) pairs[gb + k] = stage[lo + k];
    }
  }
}

// ---------------- pass2: within-bucket counting sort (unchanged) ----------------

__global__ __launch_bounds__(512) void build_pass2(const int* __restrict__ pairs,
                                                   const int* __restrict__ bucket_cnt,
                                                   int2* __restrict__ rowBE,
                                                   int* __restrict__ csr) {
  __shared__ int cnt_s[256];
  __shared__ int buf[256];
  __shared__ int ssrc[BCAP];
  int t = threadIdx.x;
  int b = blockIdx.x;
  int cnt = bucket_cnt[b];
  int gbase = b * BCAP;
  const int* pp = pairs + gbase;
  if (t < 256) cnt_s[t] = 0;
  __syncthreads();
  for (int i = t; i < cnt; i += 512) atomicAdd(&cnt_s[pp[i] & 255], 1);
  __syncthreads();
  int v = 0;
  if (t < 256) { v = cnt_s[t]; buf[t] = v; }
  __syncthreads();
  for (int off = 1; off < 256; off <<= 1) {
    int add = (t >= off && t < 256) ? buf[t - off] : 0;
    __syncthreads();
    if (t < 256) buf[t] += add;
    __syncthreads();
  }
  if (t < 256) {
    int excl = buf[t] - v;
    int node = (b << 8) + t;
    if (node < N_NODES) rowBE[node] = make_int2(gbase + excl, gbase + excl + v);
    cnt_s[t] = excl;
  }
  __syncthreads();
  for (int i = t; i < cnt; i += 512) {
    int p = pp[i];
    int pos = atomicAdd(&cnt_s[p & 255], 1);
    ssrc[pos] = p >> 8;
  }
  __syncthreads();
  for (int i = t; i < cnt; i += 512) csr[gbase + i] = ssrc[i];
}

// ---------------- fused GIN layer v4: global_load_lds staged gather with
// explicit counted vmcnt pipeline (ring of 8 groups x 4 rows), ds_read_b128
// consume, quadrant-partial accumulators; MFMA MLP unchanged ----------------

__device__ __forceinline__ void issue_group(const char* xb, char* stw, int g,
                                            int sidx, int cnt, int lane) {
  int k0 = g * 4;  // edge index base within 64-chunk (<= 60)
  int r0 = (k0 + 0 < cnt) ? __builtin_amdgcn_readlane(sidx, k0 + 0) : ZROW;
  int r1 = (k0 + 1 < cnt) ? __builtin_amdgcn_readlane(sidx, k0 + 1) : ZROW;
  int r2 = (k0 + 2 < cnt) ? __builtin_amdgcn_readlane(sidx, k0 + 2) : ZROW;
  int r3 = (k0 + 3 < cnt) ? __builtin_amdgcn_readlane(sidx, k0 + 3) : ZROW;
  int q = lane >> 4;
  int row = (q == 0) ? r0 : (q == 1) ? r1 : (q == 2) ? r2 : r3;
  const void* gp = xb + ((size_t)(unsigned)row << 8) + (lane & 15) * 16;
  void* lp = (void*)(stw + (g & 7) * 1024);  // HW writes lp + 16*lane (linear)
  __builtin_amdgcn_global_load_lds((const __attribute__((address_space(1))) void*)gp,
                                   (__attribute__((address_space(3))) void*)lp, 16, 0, 0);
}

__global__ __launch_bounds__(256, 4) void gin_layer(const unsigned short* __restrict__ xin,
                                                    const int2* __restrict__ rowBE,
                                                    const int* __restrict__ csr,
                                                    const short* __restrict__ B1f,
                                                    const float* __restrict__ b1,
                                                    const short* __restrict__ B2f,
                                                    const float* __restrict__ b2,
                                                    unsigned short* __restrict__ xout) {
  __shared__ short hbuf[16 * LSTR];                         // 4224 B
  __shared__ __align__(16) char stagebuf[4][8][1024];       // 32 KB: 4 waves x 8-group ring
  int t = threadIdx.x;
  int w = t >> 6, lane = t & 63;
  int node0 = blockIdx.x * 16;        // grid 3125: exact cover of 50000
  const char* xb = (const char*)xin;
  char* stw = &stagebuf[w][0][0];

  for (int i = 0; i < 4; ++i) {
    int node = node0 + w * 4 + i;
    int2 be = rowBE[node];
    int beg = be.x, end = be.y;

    // init: quadrant 0 holds own row (h = x + agg); quadrants 1-3 start at 0
    float acc[8];
    {
      uint4 v = *(const uint4*)(xb + ((size_t)node << 8) + (lane & 15) * 16);
      bool q0 = (lane >> 4) == 0;
      acc[0] = q0 ? bf_lo(v.x) : 0.f; acc[1] = q0 ? bf_hi(v.x) : 0.f;
      acc[2] = q0 ? bf_lo(v.y) : 0.f; acc[3] = q0 ? bf_hi(v.y) : 0.f;
      acc[4] = q0 ? bf_lo(v.z) : 0.f; acc[5] = q0 ? bf_hi(v.z) : 0.f;
      acc[6] = q0 ? bf_lo(v.w) : 0.f; acc[7] = q0 ? bf_hi(v.w) : 0.f;
    }

    for (int e = beg; e < end; e += 64) {
      int cnt = min(64, end - e);
      int sidx = (e + lane < end) ? csr[e + lane] : ZROW;  // vector load; compiler waits before readlane
      int ng = (cnt + 3) >> 2;        // 4-row groups
      int ngp = (ng + 3) & ~3;        // pad to 4-group blocks (padded groups -> ZROW, adds 0)
      int nb = ngp >> 2;
      int npro = min(ngp, 8);
      for (int g = 0; g < npro; ++g) issue_group(xb, stw, g, sidx, cnt, lane);
      for (int b = 0; b < nb; ++b) {
        if (b == nb - 1) asm volatile("s_waitcnt vmcnt(0)" ::: "memory");
        else             asm volatile("s_waitcnt vmcnt(4)" ::: "memory");
#pragma unroll
        for (int j = 0; j < 4; ++j) {
          int gs = (b * 4 + j) & 7;
          uint4 v = *(const uint4*)(stw + gs * 1024 + lane * 16);  // ds_read_b128, conflict-free
          acc[0] += bf_lo(v.x); acc[1] += bf_hi(v.x);
          acc[2] += bf_lo(v.y); acc[3] += bf_hi(v.y);
          acc[4] += bf_lo(v.z); acc[5] += bf_hi(v.z);
          acc[6] += bf_lo(v.w); acc[7] += bf_hi(v.w);
        }
        int glo = 8 + b * 4, ghi = min(ngp, 12 + b * 4);
        for (int g = glo; g < ghi; ++g) issue_group(xb, stw, g, sidx, cnt, lane);
      }
    }

    // reduce quadrant partials: lanes {m, m+16, m+32, m+48} hold same 8 columns
#pragma unroll
    for (int j = 0; j < 8; ++j) {
      acc[j] += __shfl_xor(acc[j], 16, 64);
      acc[j] += __shfl_xor(acc[j], 32, 64);
    }
    if (lane < 16) {
      short8 s;
#pragma unroll
      for (int j = 0; j < 8; ++j) s[j] = f2bf(acc[j]);
      *(short8*)&hbuf[(w * 4 + i) * LSTR + lane * 8] = s;
    }
  }
  __syncthreads();

  int q = lane >> 4, m = lane & 15;
  short8 a0f[4];
#pragma unroll
  for (int kk = 0; kk < 4; ++kk)
    a0f[kk] = *(short8*)&hbuf[m * LSTR + kk * 32 + q * 8];
  __syncthreads();

  f32x4 acc[2] = {};
#pragma unroll
  for (int kk = 0; kk < 4; ++kk)
#pragma unroll
    for (int j = 0; j < 2; ++j) {
      int nt = w * 2 + j;
      short8 bf = *(const short8*)&B1f[((nt * 4 + kk) * 64 + lane) * 8];
      acc[j] = __builtin_amdgcn_mfma_f32_16x16x32_bf16(a0f[kk], bf, acc[j], 0, 0, 0);
    }
#pragma unroll
  for (int j = 0; j < 2; ++j) {
    int nt = w * 2 + j;
    float bv = b1[nt * 16 + m];
#pragma unroll
    for (int r = 0; r < 4; ++r)
      hbuf[(q * 4 + r) * LSTR + nt * 16 + m] = f2bf(fmaxf(acc[j][r] + bv, 0.f));
  }
  __syncthreads();

  short8 a1f[4];
#pragma unroll
  for (int kk = 0; kk < 4; ++kk)
    a1f[kk] = *(short8*)&hbuf[m * LSTR + kk * 32 + q * 8];
  __syncthreads();

  f32x4 acc2[2] = {};
#pragma unroll
  for (int kk = 0; kk < 4; ++kk)
#pragma unroll
    for (int j = 0; j < 2; ++j) {
      int nt = w * 2 + j;
      short8 bf = *(const short8*)&B2f[((nt * 4 + kk) * 64 + lane) * 8];
      acc2[j] = __builtin_amdgcn_mfma_f32_16x16x32_bf16(a1f[kk], bf, acc2[j], 0, 0, 0);
    }
#pragma unroll
  for (int j = 0; j < 2; ++j) {
    int nt = w * 2 + j;
    float bv = b2[nt * 16 + m];
#pragma unroll
    for (int r = 0; r < 4; ++r)
      hbuf[(q * 4 + r) * LSTR + nt * 16 + m] = f2bf(acc2[j][r] + bv);
  }
  __syncthreads();

  {
    int row = t >> 4, c8 = t & 15;
    short8 vv = *(short8*)&hbuf[row * LSTR + c8 * 8];
    *(short8*)&xout[(size_t)(node0 + row) * D + c8 * 8] = vv;
  }
}

// ---------------- predictor: explicit 16-deep prefetch staging (unchanged) ----------------

__global__ __launch_bounds__(256, 4) void pred_kernel(const unsigned short* __restrict__ x,
                                                      const int* __restrict__ cand,
                                                      const short* __restrict__ Wf,
                                                      const int* __restrict__ ep,
                                                      const float* __restrict__ W1,
                                                      const float* __restrict__ b1,
                                                      const float* __restrict__ w2,
                                                      const float* __restrict__ b2,
                                                      float* __restrict__ out) {
  __shared__ short sS[16384];
  __shared__ short sD[16384];
  __shared__ float su[128], sv[128];
  __shared__ float partb[2][128];
  __shared__ float tvec_s[128];
  int t = threadIdx.x;
  int blockRow = blockIdx.x * 128;
  int w = t >> 6, lane = t & 63;

  if (t < 128) {
    int u = ep[0], vv = ep[1];
    su[t] = bfu(x[(size_t)u * D + t]);
    sv[t] = bfu(x[(size_t)vv * D + t]);
  }

  short8 U[8], V[8];
#pragma unroll
  for (int i = 0; i < 8; ++i) {
    int idx = t + i * 256;
    int c = blockRow + (idx >> 4);
    int2 uv = ((const int2*)cand)[c];
    int j8 = idx & 15;
    U[i] = *(const short8*)&x[(size_t)uv.x * D + j8 * 8];
    V[i] = *(const short8*)&x[(size_t)uv.y * D + j8 * 8];
  }
#pragma unroll
  for (int i = 0; i < 8; ++i) {
    int idx = t + i * 256;
    int m = idx >> 4, j8 = idx & 15;
    short8 ss, sd;
#pragma unroll
    for (int j = 0; j < 8; ++j) {
      float uf = bfu((unsigned short)U[i][j]);
      float vf = bfu((unsigned short)V[i][j]);
      ss[j] = f2bf(uf + vf);
      sd[j] = f2bf(fabsf(uf - vf));
    }
    int kk = j8 >> 2, qq = j8 & 3, mt = m >> 4, ln = (m & 15) | (qq << 4);
    int slot = ((mt * 4 + kk) * 64 + ln) * 8;
    *(short8*)&sS[slot] = ss;
    *(short8*)&sD[slot] = sd;
  }
  __syncthreads();

  {
    int j = t & 127, seg = t >> 7;
    const float* Wp = W1 + seg * 128 * D;
    float acc = 0.f;
#pragma unroll 8
    for (int k = 0; k < 128; ++k) {
      float f = seg ? fabsf(su[k] - sv[k]) : (su[k] + sv[k]);
      acc += f * Wp[k * D + j];
    }
    partb[seg][j] = acc;
  }
  __syncthreads();
  if (t < 128) tvec_s[t] = b1[t] + partb[0][t] + partb[1][t];
  __syncthreads();

  f32x4 acc[2][8] = {};
  const short* B0 = Wf + 6 * 16384;
  const short* B1 = Wf + 7 * 16384;
  for (int kk = 0; kk < 4; ++kk) {
    short8 a0[2], a1[2];
#pragma unroll
    for (int mt = 0; mt < 2; ++mt) {
      a0[mt] = *(short8*)&sS[(((w * 2 + mt) * 4 + kk) * 64 + lane) * 8];
      a1[mt] = *(short8*)&sD[(((w * 2 + mt) * 4 + kk) * 64 + lane) * 8];
    }
#pragma unroll
    for (int nt = 0; nt < 8; ++nt) {
      short8 b0 = *(const short8*)&B0[((nt * 4 + kk) * 64 + lane) * 8];
      short8 b1f = *(const short8*)&B1[((nt * 4 + kk) * 64 + lane) * 8];
#pragma unroll
      for (int mt = 0; mt < 2; ++mt) {
        acc[mt][nt] = __builtin_amdgcn_mfma_f32_16x16x32_bf16(a0[mt], b0, acc[mt][nt], 0, 0, 0);
        acc[mt][nt] = __builtin_amdgcn_mfma_f32_16x16x32_bf16(a1[mt], b1f, acc[mt][nt], 0, 0, 0);
      }
    }
  }

  int colbase = lane & 15, rq = lane >> 4;
  float tv[8], w2v[8];
#pragma unroll
  for (int nt = 0; nt < 8; ++nt) {
    tv[nt] = tvec_s[nt * 16 + colbase];
    w2v[nt] = w2[nt * 16 + colbase];
  }
  float b2v = b2[0];
#pragma unroll
  for (int mt = 0; mt < 2; ++mt) {
    float part[4] = {0.f, 0.f, 0.f, 0.f};
#pragma unroll
    for (int nt = 0; nt < 8; ++nt)
#pragma unroll
      for (int r = 0; r < 4; ++r) {
        float h = acc[mt][nt][r] + tv[nt];
        h = fmaxf(h, 0.f);
        part[r] += h * w2v[nt];
      }
#pragma unroll
    for (int r = 0; r < 4; ++r)
      for (int msk = 1; msk < 16; msk <<= 1)
        part[r] += __shfl_xor(part[r], msk, 64);
    if (colbase == 0) {
      int row0 = blockRow + (w * 2 + mt) * 16 + rq * 4;
#pragma unroll
      for (int r = 0; r < 4; ++r) out[row0 + r] = part[r] + b2v;
    }
  }
}

// ---------------- launch ----------------

extern "C" void kernel_launch(void* const* d_in, const int* in_sizes, int n_in,
                              void* d_out, int out_size, void* d_ws, size_t ws_size,
                              hipStream_t stream) {
  const float* x_in = (const float*)d_in[0];
  const int* edge_index = (const int*)d_in[1];
  const int* ep = (const int*)d_in[2];
  const int* cand = (const int*)d_in[3];
  const float* gw1 = (const float*)d_in[4];
  const float* gb1 = (const float*)d_in[5];
  const float* gw2 = (const float*)d_in[6];
  const float* gb2 = (const float*)d_in[7];
  const float* pw1 = (const float*)d_in[8];
  const float* pb1 = (const float*)d_in[9];
  const float* pw2 = (const float*)d_in[10];
  const float* pb2 = (const float*)d_in[11];
  float* out = (float*)d_out;

  char* ws = (char*)d_ws;
  size_t off = 0;
  auto alloc = [&](size_t bytes) {
    void* p = ws + off;
    off += (bytes + 255) & ~(size_t)255;
    return p;
  };
  unsigned short* xA = (unsigned short*)alloc((size_t)ROWS * D * 2);
  unsigned short* xB = (unsigned short*)alloc((size_t)ROWS * D * 2);
  int* pairs       = (int*)alloc((size_t)NB * BCAP * 4);
  int* csr         = (int*)alloc((size_t)NB * BCAP * 4);
  int2* rowBE      = (int2*)alloc((size_t)N_NODES * 8);
  int* bucket_cnt  = (int*)alloc((size_t)NB * 4);
  short* Wf        = (short*)alloc((size_t)8 * 16384 * 2);

  const int* src = edge_index;
  const int* dst = edge_index + N_EDGES;

  hipMemsetAsync(bucket_cnt, 0, (size_t)NB * 4, stream);
  // zero the /dev/null row used by padded gather slots (both ping-pong buffers)
  hipMemsetAsync(xA + (size_t)ZROW * D, 0, (size_t)D * 2, stream);
  hipMemsetAsync(xB + (size_t)ZROW * D, 0, (size_t)D * 2, stream);

  prep_pass1<<<3580, 256, 0, stream>>>(gw1, gw2, pw1, Wf, x_in, xA, src, dst, bucket_cnt, pairs);
  build_pass2<<<NB, 512, 0, stream>>>(pairs, bucket_cnt, rowBE, csr);

  const int gin_grid = N_NODES / 16;  // 3125
  gin_layer<<<gin_grid, 256, 0, stream>>>(xA, rowBE, csr, Wf + 0 * 16384, gb1 + 0 * D,
                                          Wf + 3 * 16384, gb2 + 0 * D, xB);
  gin_layer<<<gin_grid, 256, 0, stream>>>(xB, rowBE, csr, Wf + 1 * 16384, gb1 + 1 * D,
                                          Wf + 4 * 16384, gb2 + 1 * D, xA);
  gin_layer<<<gin_grid, 256, 0, stream>>>(xA, rowBE, csr, Wf + 2 * 16384, gb1 + 2 * D,
                                          Wf + 5 * 16384, gb2 + 2 * D, xB);

  pred_kernel<<<N_CAND / 128, 256, 0, stream>>>(xB, cand, Wf, ep, pw1, pb1, pw2, pb2, out);
}

// Round 5
// 341.863 us; speedup vs baseline: 1.1386x; 1.1386x over previous
//
#include <hip/hip_runtime.h>

#define N_NODES 50000
#define N_EDGES 1600000
#define N_CAND  131072
#define D 128
#define ROWS 50176   // padded row count
#define NB 196       // coarse buckets (dst>>8)
#define BCAP 10240   // fixed per-bucket capacity (E[cnt]=8192, sigma~90)
#define LSTR 132     // LDS row stride (bf16 elems)
#define ZROW 50000   // zeroed row: /dev/null target for padded gather slots

typedef __attribute__((ext_vector_type(8))) short short8;
typedef __attribute__((ext_vector_type(4))) float f32x4;
typedef __attribute__((ext_vector_type(4))) unsigned int u32x4;

__device__ inline short f2bf(float f) {
  unsigned u = __builtin_bit_cast(unsigned, f);
  u = (u + 0x7FFFu + ((u >> 16) & 1u)) >> 16;
  return (short)u;
}
__device__ inline float bf_lo(unsigned u) { return __builtin_bit_cast(float, u << 16); }
__device__ inline float bf_hi(unsigned u) { return __builtin_bit_cast(float, u & 0xFFFF0000u); }
__device__ inline float bfu(unsigned short h) { return __builtin_bit_cast(float, (unsigned)h << 16); }

// ---------------- prep + pass1 merged (unchanged) ----------------

__global__ __launch_bounds__(256) void prep_pass1(const float* __restrict__ gw1,
                                                  const float* __restrict__ gw2,
                                                  const float* __restrict__ pw1,
                                                  short* __restrict__ Wf,
                                                  const float* __restrict__ x,
                                                  unsigned short* __restrict__ y,
                                                  const int* __restrict__ src,
                                                  const int* __restrict__ dst,
                                                  int* __restrict__ bucket_cnt,
                                                  int* __restrict__ pairs) {
  int b = blockIdx.x;
  int t = threadIdx.x;
  if (b < 64) {
    int tid = b * 256 + t;  // 0..16383
    int img = tid >> 11, idx = tid & 2047;
    const float* W;
    if (img < 3) W = gw1 + img * 16384;
    else if (img < 6) W = gw2 + (img - 3) * 16384;
    else W = pw1 + (256 + (img - 6) * 128) * 128;
    int n = idx & 127, k8 = idx >> 7;
    short8 s;
#pragma unroll
    for (int j = 0; j < 8; ++j) s[j] = f2bf(W[(k8 * 8 + j) * 128 + n]);
    int kk = k8 >> 2, q = k8 & 3, nt = n >> 4, ln = (n & 15) | (q << 4);
    *(short8*)&Wf[img * 16384 + ((nt * 4 + kk) * 64 + ln) * 8] = s;
  } else if (b < 3189) {
    size_t base = ((size_t)(b - 64) * 256 + t) * 8;
    float4 v0 = *(const float4*)&x[base];
    float4 v1 = *(const float4*)&x[base + 4];
    short8 s;
    s[0] = f2bf(v0.x); s[1] = f2bf(v0.y); s[2] = f2bf(v0.z); s[3] = f2bf(v0.w);
    s[4] = f2bf(v1.x); s[5] = f2bf(v1.y); s[6] = f2bf(v1.z); s[7] = f2bf(v1.w);
    *(short8*)&y[base] = s;
  } else {
    __shared__ int lcnt[NB];
    __shared__ int loff[NB];
    __shared__ int gbase[NB];
    __shared__ int scanbuf[256];
    __shared__ int stage[4096];
    int e0 = (b - 3189) * 4096;
    for (int i = t; i < NB; i += 256) lcnt[i] = 0;
    __syncthreads();
    int d[16], s[16], r[16];
#pragma unroll
    for (int i = 0; i < 16; ++i) {
      int e = e0 + i * 256 + t;
      if (e < N_EDGES) {
        d[i] = dst[e]; s[i] = src[e];
        r[i] = atomicAdd(&lcnt[d[i] >> 8], 1);
      } else d[i] = -1;
    }
    __syncthreads();
    {
      int v = (t < NB) ? lcnt[t] : 0;
      scanbuf[t] = v;
      __syncthreads();
      for (int off = 1; off < 256; off <<= 1) {
        int add = (t >= off) ? scanbuf[t - off] : 0;
        __syncthreads();
        scanbuf[t] += add;
        __syncthreads();
      }
      if (t < NB) {
        loff[t] = scanbuf[t] - v;
        gbase[t] = v ? atomicAdd(&bucket_cnt[t], v) : 0;
      }
    }
    __syncthreads();
#pragma unroll
    for (int i = 0; i < 16; ++i) {
      if (d[i] >= 0) {
        int bb = d[i] >> 8;
        stage[loff[bb] + r[i]] = (s[i] << 8) | (d[i] & 255);
      }
    }
    __syncthreads();
    int w = t >> 6, lane = t & 63;
    for (int bb = w; bb < NB; bb += 4) {
      int c = lcnt[bb], lo = loff[bb], gb = bb * BCAP + gbase[bb];
      for (int k = lane; k < c; k += 64) pairs[gb + k] = stage[lo + k];
    }
  }
}

// ---------------- pass2: within-bucket counting sort (unchanged) ----------------

__global__ __launch_bounds__(512) void build_pass2(const int* __restrict__ pairs,
                                                   const int* __restrict__ bucket_cnt,
                                                   int2* __restrict__ rowBE,
                                                   int* __restrict__ csr) {
  __shared__ int cnt_s[256];
  __shared__ int buf[256];
  __shared__ int ssrc[BCAP];
  int t = threadIdx.x;
  int b = blockIdx.x;
  int cnt = bucket_cnt[b];
  int gbase = b * BCAP;
  const int* pp = pairs + gbase;
  if (t < 256) cnt_s[t] = 0;
  __syncthreads();
  for (int i = t; i < cnt; i += 512) atomicAdd(&cnt_s[pp[i] & 255], 1);
  __syncthreads();
  int v = 0;
  if (t < 256) { v = cnt_s[t]; buf[t] = v; }
  __syncthreads();
  for (int off = 1; off < 256; off <<= 1) {
    int add = (t >= off && t < 256) ? buf[t - off] : 0;
    __syncthreads();
    if (t < 256) buf[t] += add;
    __syncthreads();
  }
  if (t < 256) {
    int excl = buf[t] - v;
    int node = (b << 8) + t;
    if (node < N_NODES) rowBE[node] = make_int2(gbase + excl, gbase + excl + v);
    cnt_s[t] = excl;
  }
  __syncthreads();
  for (int i = t; i < cnt; i += 512) {
    int p = pp[i];
    int pos = atomicAdd(&cnt_s[p & 255], 1);
    ssrc[pos] = p >> 8;
  }
  __syncthreads();
  for (int i = t; i < cnt; i += 512) csr[gbase + i] = ssrc[i];
}

// ---------------- fused GIN layer v5: 4-rows-per-dwordx4 register gather.
// ds_bpermute index distribution (lgkm domain; never drains vmcnt), inline-asm
// global_load_dwordx4 into named ping-pong groups (compiler can't serialize),
// counted s_waitcnt vmcnt(4/0). Quadrant partials + shfl reduce. MLP unchanged. ----

// issue one batch (4 rows): quadrant q reads row sidx[gb4+b+? ...]
#define ISSUE_B(gb_, b_, dst_) {                                               \
    int idx_ = __builtin_amdgcn_ds_bpermute((((gb_) + (b_)) << 4) + qb, sidx); \
    int pos_ = e + (((gb_) + (b_)) << 2) + qid;                                \
    idx_ = (pos_ < end) ? idx_ : ZROW;                                         \
    int voff_ = (idx_ << 8) + colb;                                            \
    asm volatile("global_load_dwordx4 %0, %1, %2"                             \
                 : "=v"(dst_) : "v"(voff_), "s"(xbase) : "memory");            }

#define ISSUE_G(gb_, d0_, d1_, d2_, d3_) {  \
    ISSUE_B(gb_, 0, d0_); ISSUE_B(gb_, 1, d1_); ISSUE_B(gb_, 2, d2_); ISSUE_B(gb_, 3, d3_); }

#define WAITV(n_) { asm volatile("s_waitcnt vmcnt(" #n_ ")" ::: "memory"); \
                    __builtin_amdgcn_sched_barrier(0); }

#define ACCUM(v_) {                                             \
    acc[0] += bf_lo((v_)[0]); acc[1] += bf_hi((v_)[0]);         \
    acc[2] += bf_lo((v_)[1]); acc[3] += bf_hi((v_)[1]);         \
    acc[4] += bf_lo((v_)[2]); acc[5] += bf_hi((v_)[2]);         \
    acc[6] += bf_lo((v_)[3]); acc[7] += bf_hi((v_)[3]); }

#define CONS_G(d0_, d1_, d2_, d3_) { ACCUM(d0_); ACCUM(d1_); ACCUM(d2_); ACCUM(d3_); }

__global__ __launch_bounds__(256, 4) void gin_layer(const unsigned short* __restrict__ xin,
                                                    const int2* __restrict__ rowBE,
                                                    const int* __restrict__ csr,
                                                    const short* __restrict__ B1f,
                                                    const float* __restrict__ b1,
                                                    const short* __restrict__ B2f,
                                                    const float* __restrict__ b2,
                                                    unsigned short* __restrict__ xout) {
  __shared__ short hbuf[16 * LSTR];   // 4224 B
  int t = threadIdx.x;
  int w = t >> 6, lane = t & 63;
  int qid = lane >> 4;                // quadrant = row-within-batch
  int qb = qid << 2;                  // bpermute addr component
  int colb = (lane & 15) * 16;        // byte column within row
  int node0 = blockIdx.x * 16;        // grid 3125: exact cover of 50000
  const char* xb = (const char*)xin;
  unsigned long long xbase = (unsigned long long)xb;

#pragma unroll 1
  for (int i = 0; i < 4; ++i) {
    int node = node0 + w * 4 + i;
    int2 be = rowBE[node];
    int beg = be.x, end = be.y;

    // quadrant-partial accumulators; q0 seeded with own row (h = x + agg)
    float acc[8];
    {
      u32x4 v = *(const u32x4*)(xb + ((size_t)node << 8) + colb);
      bool q0 = (qid == 0);
      acc[0] = q0 ? bf_lo(v[0]) : 0.f; acc[1] = q0 ? bf_hi(v[0]) : 0.f;
      acc[2] = q0 ? bf_lo(v[1]) : 0.f; acc[3] = q0 ? bf_hi(v[1]) : 0.f;
      acc[4] = q0 ? bf_lo(v[2]) : 0.f; acc[5] = q0 ? bf_hi(v[2]) : 0.f;
      acc[6] = q0 ? bf_lo(v[3]) : 0.f; acc[7] = q0 ? bf_hi(v[3]) : 0.f;
    }

#pragma unroll 1
    for (int e = beg; e < end; e += 64) {
      int cnt = min(64, end - e);
      int sidx = (e + lane < end) ? csr[e + lane] : 0;  // compiler drains vmcnt before bperm use (pipeline empty here)
      int ngrp = (cnt + 15) >> 4;   // 16-row groups, 1..4
      u32x4 A0, A1, A2, A3, B0, B1, B2, B3;
      switch (ngrp) {
        case 1:
          ISSUE_G(0, A0, A1, A2, A3);
          WAITV(0); CONS_G(A0, A1, A2, A3);
          break;
        case 2:
          ISSUE_G(0, A0, A1, A2, A3);
          ISSUE_G(4, B0, B1, B2, B3);
          WAITV(4); CONS_G(A0, A1, A2, A3);
          WAITV(0); CONS_G(B0, B1, B2, B3);
          break;
        case 3:
          ISSUE_G(0, A0, A1, A2, A3);
          ISSUE_G(4, B0, B1, B2, B3);
          WAITV(4); CONS_G(A0, A1, A2, A3);
          ISSUE_G(8, A0, A1, A2, A3);
          WAITV(4); CONS_G(B0, B1, B2, B3);
          WAITV(0); CONS_G(A0, A1, A2, A3);
          break;
        default:
          ISSUE_G(0, A0, A1, A2, A3);
          ISSUE_G(4, B0, B1, B2, B3);
          WAITV(4); CONS_G(A0, A1, A2, A3);
          ISSUE_G(8, A0, A1, A2, A3);
          WAITV(4); CONS_G(B0, B1, B2, B3);
          ISSUE_G(12, B0, B1, B2, B3);
          WAITV(4); CONS_G(A0, A1, A2, A3);
          WAITV(0); CONS_G(B0, B1, B2, B3);
          break;
      }
    }

    // reduce quadrant partials: lanes {m, m+16, m+32, m+48} hold same 8 columns
#pragma unroll
    for (int j = 0; j < 8; ++j) {
      acc[j] += __shfl_xor(acc[j], 16, 64);
      acc[j] += __shfl_xor(acc[j], 32, 64);
    }
    if (lane < 16) {
      short8 s;
#pragma unroll
      for (int j = 0; j < 8; ++j) s[j] = f2bf(acc[j]);
      *(short8*)&hbuf[(w * 4 + i) * LSTR + lane * 8] = s;
    }
  }
  __syncthreads();

  int q = lane >> 4, m = lane & 15;
  short8 a0f[4];
#pragma unroll
  for (int kk = 0; kk < 4; ++kk)
    a0f[kk] = *(short8*)&hbuf[m * LSTR + kk * 32 + q * 8];
  __syncthreads();

  f32x4 acc[2] = {};
#pragma unroll
  for (int kk = 0; kk < 4; ++kk)
#pragma unroll
    for (int j = 0; j < 2; ++j) {
      int nt = w * 2 + j;
      short8 bf = *(const short8*)&B1f[((nt * 4 + kk) * 64 + lane) * 8];
      acc[j] = __builtin_amdgcn_mfma_f32_16x16x32_bf16(a0f[kk], bf, acc[j], 0, 0, 0);
    }
#pragma unroll
  for (int j = 0; j < 2; ++j) {
    int nt = w * 2 + j;
    float bv = b1[nt * 16 + m];
#pragma unroll
    for (int r = 0; r < 4; ++r)
      hbuf[(q * 4 + r) * LSTR + nt * 16 + m] = f2bf(fmaxf(acc[j][r] + bv, 0.f));
  }
  __syncthreads();

  short8 a1f[4];
#pragma unroll
  for (int kk = 0; kk < 4; ++kk)
    a1f[kk] = *(short8*)&hbuf[m * LSTR + kk * 32 + q * 8];
  __syncthreads();

  f32x4 acc2[2] = {};
#pragma unroll
  for (int kk = 0; kk < 4; ++kk)
#pragma unroll
    for (int j = 0; j < 2; ++j) {
      int nt = w * 2 + j;
      short8 bf = *(const short8*)&B2f[((nt * 4 + kk) * 64 + lane) * 8];
      acc2[j] = __builtin_amdgcn_mfma_f32_16x16x32_bf16(a1f[kk], bf, acc2[j], 0, 0, 0);
    }
#pragma unroll
  for (int j = 0; j < 2; ++j) {
    int nt = w * 2 + j;
    float bv = b2[nt * 16 + m];
#pragma unroll
    for (int r = 0; r < 4; ++r)
      hbuf[(q * 4 + r) * LSTR + nt * 16 + m] = f2bf(acc2[j][r] + bv);
  }
  __syncthreads();

  {
    int row = t >> 4, c8 = t & 15;
    short8 vv = *(short8*)&hbuf[row * LSTR + c8 * 8];
    *(short8*)&xout[(size_t)(node0 + row) * D + c8 * 8] = vv;
  }
}

// ---------------- predictor: explicit 16-deep prefetch staging (unchanged) ----------------

__global__ __launch_bounds__(256, 4) void pred_kernel(const unsigned short* __restrict__ x,
                                                      const int* __restrict__ cand,
                                                      const short* __restrict__ Wf,
                                                      const int* __restrict__ ep,
                                                      const float* __restrict__ W1,
                                                      const float* __restrict__ b1,
                                                      const float* __restrict__ w2,
                                                      const float* __restrict__ b2,
                                                      float* __restrict__ out) {
  __shared__ short sS[16384];
  __shared__ short sD[16384];
  __shared__ float su[128], sv[128];
  __shared__ float partb[2][128];
  __shared__ float tvec_s[128];
  int t = threadIdx.x;
  int blockRow = blockIdx.x * 128;
  int w = t >> 6, lane = t & 63;

  if (t < 128) {
    int u = ep[0], vv = ep[1];
    su[t] = bfu(x[(size_t)u * D + t]);
    sv[t] = bfu(x[(size_t)vv * D + t]);
  }

  short8 U[8], V[8];
#pragma unroll
  for (int i = 0; i < 8; ++i) {
    int idx = t + i * 256;
    int c = blockRow + (idx >> 4);
    int2 uv = ((const int2*)cand)[c];
    int j8 = idx & 15;
    U[i] = *(const short8*)&x[(size_t)uv.x * D + j8 * 8];
    V[i] = *(const short8*)&x[(size_t)uv.y * D + j8 * 8];
  }
#pragma unroll
  for (int i = 0; i < 8; ++i) {
    int idx = t + i * 256;
    int m = idx >> 4, j8 = idx & 15;
    short8 ss, sd;
#pragma unroll
    for (int j = 0; j < 8; ++j) {
      float uf = bfu((unsigned short)U[i][j]);
      float vf = bfu((unsigned short)V[i][j]);
      ss[j] = f2bf(uf + vf);
      sd[j] = f2bf(fabsf(uf - vf));
    }
    int kk = j8 >> 2, qq = j8 & 3, mt = m >> 4, ln = (m & 15) | (qq << 4);
    int slot = ((mt * 4 + kk) * 64 + ln) * 8;
    *(short8*)&sS[slot] = ss;
    *(short8*)&sD[slot] = sd;
  }
  __syncthreads();

  {
    int j = t & 127, seg = t >> 7;
    const float* Wp = W1 + seg * 128 * D;
    float acc = 0.f;
#pragma unroll 8
    for (int k = 0; k < 128; ++k) {
      float f = seg ? fabsf(su[k] - sv[k]) : (su[k] + sv[k]);
      acc += f * Wp[k * D + j];
    }
    partb[seg][j] = acc;
  }
  __syncthreads();
  if (t < 128) tvec_s[t] = b1[t] + partb[0][t] + partb[1][t];
  __syncthreads();

  f32x4 acc[2][8] = {};
  const short* B0 = Wf + 6 * 16384;
  const short* B1 = Wf + 7 * 16384;
  for (int kk = 0; kk < 4; ++kk) {
    short8 a0[2], a1[2];
#pragma unroll
    for (int mt = 0; mt < 2; ++mt) {
      a0[mt] = *(short8*)&sS[(((w * 2 + mt) * 4 + kk) * 64 + lane) * 8];
      a1[mt] = *(short8*)&sD[(((w * 2 + mt) * 4 + kk) * 64 + lane) * 8];
    }
#pragma unroll
    for (int nt = 0; nt < 8; ++nt) {
      short8 b0 = *(const short8*)&B0[((nt * 4 + kk) * 64 + lane) * 8];
      short8 b1f = *(const short8*)&B1[((nt * 4 + kk) * 64 + lane) * 8];
#pragma unroll
      for (int mt = 0; mt < 2; ++mt) {
        acc[mt][nt] = __builtin_amdgcn_mfma_f32_16x16x32_bf16(a0[mt], b0, acc[mt][nt], 0, 0, 0);
        acc[mt][nt] = __builtin_amdgcn_mfma_f32_16x16x32_bf16(a1[mt], b1f, acc[mt][nt], 0, 0, 0);
      }
    }
  }

  int colbase = lane & 15, rq = lane >> 4;
  float tv[8], w2v[8];
#pragma unroll
  for (int nt = 0; nt < 8; ++nt) {
    tv[nt] = tvec_s[nt * 16 + colbase];
    w2v[nt] = w2[nt * 16 + colbase];
  }
  float b2v = b2[0];
#pragma unroll
  for (int mt = 0; mt < 2; ++mt) {
    float part[4] = {0.f, 0.f, 0.f, 0.f};
#pragma unroll
    for (int nt = 0; nt < 8; ++nt)
#pragma unroll
      for (int r = 0; r < 4; ++r) {
        float h = acc[mt][nt][r] + tv[nt];
        h = fmaxf(h, 0.f);
        part[r] += h * w2v[nt];
      }
#pragma unroll
    for (int r = 0; r < 4; ++r)
      for (int msk = 1; msk < 16; msk <<= 1)
        part[r] += __shfl_xor(part[r], msk, 64);
    if (colbase == 0) {
      int row0 = blockRow + (w * 2 + mt) * 16 + rq * 4;
#pragma unroll
      for (int r = 0; r < 4; ++r) out[row0 + r] = part[r] + b2v;
    }
  }
}

// ---------------- launch ----------------

extern "C" void kernel_launch(void* const* d_in, const int* in_sizes, int n_in,
                              void* d_out, int out_size, void* d_ws, size_t ws_size,
                              hipStream_t stream) {
  const float* x_in = (const float*)d_in[0];
  const int* edge_index = (const int*)d_in[1];
  const int* ep = (const int*)d_in[2];
  const int* cand = (const int*)d_in[3];
  const float* gw1 = (const float*)d_in[4];
  const float* gb1 = (const float*)d_in[5];
  const float* gw2 = (const float*)d_in[6];
  const float* gb2 = (const float*)d_in[7];
  const float* pw1 = (const float*)d_in[8];
  const float* pb1 = (const float*)d_in[9];
  const float* pw2 = (const float*)d_in[10];
  const float* pb2 = (const float*)d_in[11];
  float* out = (float*)d_out;

  char* ws = (char*)d_ws;
  size_t off = 0;
  auto alloc = [&](size_t bytes) {
    void* p = ws + off;
    off += (bytes + 255) & ~(size_t)255;
    return p;
  };
  unsigned short* xA = (unsigned short*)alloc((size_t)ROWS * D * 2);
  unsigned short* xB = (unsigned short*)alloc((size_t)ROWS * D * 2);
  int* pairs       = (int*)alloc((size_t)NB * BCAP * 4);
  int* csr         = (int*)alloc((size_t)NB * BCAP * 4);
  int2* rowBE      = (int2*)alloc((size_t)N_NODES * 8);
  int* bucket_cnt  = (int*)alloc((size_t)NB * 4);
  short* Wf        = (short*)alloc((size_t)8 * 16384 * 2);

  const int* src = edge_index;
  const int* dst = edge_index + N_EDGES;

  hipMemsetAsync(bucket_cnt, 0, (size_t)NB * 4, stream);
  // zero the /dev/null row used by padded gather slots (both ping-pong buffers)
  hipMemsetAsync(xA + (size_t)ZROW * D, 0, (size_t)D * 2, stream);
  hipMemsetAsync(xB + (size_t)ZROW * D, 0, (size_t)D * 2, stream);

  prep_pass1<<<3580, 256, 0, stream>>>(gw1, gw2, pw1, Wf, x_in, xA, src, dst, bucket_cnt, pairs);
  build_pass2<<<NB, 512, 0, stream>>>(pairs, bucket_cnt, rowBE, csr);

  const int gin_grid = N_NODES / 16;  // 3125
  gin_layer<<<gin_grid, 256, 0, stream>>>(xA, rowBE, csr, Wf + 0 * 16384, gb1 + 0 * D,
                                          Wf + 3 * 16384, gb2 + 0 * D, xB);
  gin_layer<<<gin_grid, 256, 0, stream>>>(xB, rowBE, csr, Wf + 1 * 16384, gb1 + 1 * D,
                                          Wf + 4 * 16384, gb2 + 1 * D, xA);
  gin_layer<<<gin_grid, 256, 0, stream>>>(xA, rowBE, csr, Wf + 2 * 16384, gb1 + 2 * D,
                                          Wf + 5 * 16384, gb2 + 2 * D, xB);

  pred_kernel<<<N_CAND / 128, 256, 0, stream>>>(xB, cand, Wf, ep, pw1, pb1, pw2, pb2, out);
}